// Round 4
// baseline (652.567 us; speedup 1.0000x reference)
//
#include <hip/hip_runtime.h>
#include <hip/hip_bf16.h>

// ---------------- types ----------------
typedef __bf16 bf16_t;
typedef bf16_t bf16x8 __attribute__((ext_vector_type(8)));
typedef float f32x4 __attribute__((ext_vector_type(4)));

#define S_LEN 2048
#define L_LEN 3
#define D_DIM 128
#define NK 16
#define VOCAB 50000
#define NPAD 50048   // 391 * 128

__device__ __forceinline__ void gload16(const void* g, void* l) {
    __builtin_amdgcn_global_load_lds(
        (const __attribute__((address_space(1))) void*)g,
        (__attribute__((address_space(3))) void*)l, 16, 0, 0);
}

// ---------------- Eu: mean of 6144 gathered embedding rows ----------------
__global__ __launch_bounds__(128) void eu_kernel(const int* __restrict__ su,
                                                 const float* __restrict__ emb,
                                                 float* __restrict__ eu_sum) {
    const int t = threadIdx.x;
    const int b = blockIdx.x;           // 48 blocks, 128 rows each
    float acc = 0.f;
    for (int i = 0; i < 128; ++i) {
        int tok = su[b * 128 + i];
        acc += emb[(size_t)tok * D_DIM + t];
    }
    atomicAdd(&eu_sum[t], acc);
}

// ---------------- fc2W fp32 -> bf16, padded to NPAD rows ----------------
__global__ __launch_bounds__(256) void convB_kernel(const float* __restrict__ W,
                                                    __hip_bfloat16* __restrict__ Bb) {
    size_t gid = (size_t)blockIdx.x * 256 + threadIdx.x;
    size_t base = gid * 8;                      // element index in [NPAD*256]
    int row = (int)(base >> 8);
    float v[8];
    if (row < VOCAB) {
        float4 a = *(const float4*)&W[base];
        float4 b = *(const float4*)&W[base + 4];
        v[0]=a.x; v[1]=a.y; v[2]=a.z; v[3]=a.w; v[4]=b.x; v[5]=b.y; v[6]=b.z; v[7]=b.w;
    } else {
        #pragma unroll
        for (int i = 0; i < 8; ++i) v[i] = 0.f;
    }
    union { __hip_bfloat16 h[8]; uint4 u; } o;
    #pragma unroll
    for (int i = 0; i < 8; ++i) o.h[i] = __float2bfloat16(v[i]);
    *(uint4*)&Bb[base] = o.u;
}

// ---------------- fused per-sample pipeline ----------------
// NOTE: the reference's Bahdanau attention is an IDENTITY on Ec:
//   attn[b,s,i,d] = sum_j alpha[i,j] * Ec[b,s,i,d] = Ec[b,s,i,d]
// (Ec[:, :, :, None, :] aligns l with i, and softmax_j sums to 1), so
// Wi/Wj/Vv are dead parameters. fc1_in = [conv(16), Ec flat(384)].
__global__ __launch_bounds__(128) void persample_kernel(
    const int* __restrict__ su, const float* __restrict__ emb,
    const float* __restrict__ convK, const float* __restrict__ convb,
    const float* __restrict__ fc1W, const float* __restrict__ fc1b,
    const float* __restrict__ eu_sum, __hip_bfloat16* __restrict__ Abf) {
    __shared__ __align__(16) float fc1_in[NK + L_LEN * D_DIM];  // 400
    __shared__ float hbuf[D_DIM];
    __shared__ float redk[NK][2];
    const int s = blockIdx.x;
    const int t = threadIdx.x;
    const int lane = t & 63, w = t >> 6;

    float ecr[L_LEN];
    #pragma unroll
    for (int li = 0; li < L_LEN; ++li) {
        int tok = su[s * L_LEN + li];
        ecr[li] = emb[(size_t)tok * D_DIM + t];
        fc1_in[NK + li * D_DIM + t] = ecr[li];   // attn == Ec (identity)
    }
    const float Eut = eu_sum[t] * (1.0f / 6144.0f);

    // vertical conv partials: each wave reduces its 64 d-lanes for all k
    for (int k = 0; k < NK; ++k) {
        float p = 0.f;
        #pragma unroll
        for (int li = 0; li < L_LEN; ++li)
            p += ecr[li] * convK[k * (L_LEN * D_DIM) + li * D_DIM + t];
        #pragma unroll
        for (int off = 32; off > 0; off >>= 1) p += __shfl_down(p, off, 64);
        if (lane == 0) redk[k][w] = p;
    }
    __syncthreads();
    if (t < NK) fc1_in[t] = fmaxf(redk[t][0] + redk[t][1] + convb[t], 0.f);
    __syncthreads();

    // fc1: h[e] = relu(fc1_in . fc1W[e,:] + fc1b[e]);  thread t = e
    {
        float acc = fc1b[t];
        const float4* W4 = (const float4*)(fc1W + (size_t)t * 400);
        const float4* in4 = (const float4*)fc1_in;
        for (int x4 = 0; x4 < 100; ++x4) {
            float4 wv = W4[x4], iv = in4[x4];
            acc += wv.x * iv.x + wv.y * iv.y + wv.z * iv.z + wv.w * iv.w;
        }
        hbuf[t] = fmaxf(acc, 0.f);
    }
    __syncthreads();

    // second attention: u[i] = sum_j softmax_j(Eu[i]*h[j]) * h[j];  thread t = i
    {
        float m = -1e30f;
        for (int j = 0; j < D_DIM; ++j) m = fmaxf(m, Eut * hbuf[j]);
        float se = 0.f, sw = 0.f;
        for (int j = 0; j < D_DIM; ++j) {
            float e = expf(Eut * hbuf[j] - m);
            se += e; sw += e * hbuf[j];
        }
        float u = sw / se;
        Abf[(size_t)s * 256 + t]       = __float2bfloat16(Eut);
        Abf[(size_t)s * 256 + 128 + t] = __float2bfloat16(u);
    }
}

// ---------------- bf16 MFMA GEMM: C[2048][50000] = A[2048][256] * B[NPAD][256]^T ----------------
// 128x128 tile, BK=64, 4 waves (2x2), global_load_lds staging with XOR swizzle.
__global__ __launch_bounds__(256) void gemm_kernel(const bf16_t* __restrict__ A,
                                                   const bf16_t* __restrict__ B,
                                                   const float* __restrict__ bias,
                                                   float* __restrict__ out) {
    __shared__ __align__(16) unsigned char ldsA[128 * 128];  // 128 rows x 128B (64 bf16)
    __shared__ __align__(16) unsigned char ldsB[128 * 128];
    const int tid = threadIdx.x;
    const int l = tid & 63;
    const int w = tid >> 6;
    const int wm = w >> 1, wn = w & 1;
    const int m0 = blockIdx.x * 128;
    const int n0 = blockIdx.y * 128;

    f32x4 acc[4][4] = {};

    const char* Ab = (const char*)A + (size_t)m0 * 512;  // 256 bf16 = 512B row stride
    const char* Bb = (const char*)B + (size_t)n0 * 512;

    for (int kk = 0; kk < 4; ++kk) {
        #pragma unroll
        for (int i = 0; i < 4; ++i) {
            int row = i * 32 + (tid >> 3);
            int colb = ((tid & 7) ^ (row & 7)) << 4;  // pre-swizzled source (involution)
            gload16(Ab + (size_t)row * 512 + kk * 128 + colb, &ldsA[i * 4096 + w * 1024]);
            gload16(Bb + (size_t)row * 512 + kk * 128 + colb, &ldsB[i * 4096 + w * 1024]);
        }
        __syncthreads();
        #pragma unroll
        for (int kh = 0; kh < 2; ++kh) {
            const int koff = kh * 64 + (l >> 4) * 16;
            bf16x8 af[4], bfr[4];
            #pragma unroll
            for (int mi = 0; mi < 4; ++mi) {
                int row = wm * 64 + mi * 16 + (l & 15);
                af[mi] = *(const bf16x8*)&ldsA[row * 128 + (koff ^ ((row & 7) << 4))];
            }
            #pragma unroll
            for (int ni = 0; ni < 4; ++ni) {
                int row = wn * 64 + ni * 16 + (l & 15);
                bfr[ni] = *(const bf16x8*)&ldsB[row * 128 + (koff ^ ((row & 7) << 4))];
            }
            #pragma unroll
            for (int mi = 0; mi < 4; ++mi)
                #pragma unroll
                for (int ni = 0; ni < 4; ++ni)
                    acc[mi][ni] = __builtin_amdgcn_mfma_f32_16x16x32_bf16(
                        af[mi], bfr[ni], acc[mi][ni], 0, 0, 0);
        }
        __syncthreads();
    }

    // epilogue: += bias, predicated fp32 stores
    #pragma unroll
    for (int ni = 0; ni < 4; ++ni) {
        const int col = n0 + wn * 64 + ni * 16 + (l & 15);
        const bool ok = col < VOCAB;
        const float bv = ok ? bias[col] : 0.f;
        #pragma unroll
        for (int mi = 0; mi < 4; ++mi) {
            const int rbase = m0 + wm * 64 + mi * 16 + ((l >> 4) << 2);
            f32x4 c = acc[mi][ni];
            if (ok) {
                #pragma unroll
                for (int r = 0; r < 4; ++r)
                    out[(size_t)(rbase + r) * VOCAB + col] = c[r] + bv;
            }
        }
    }
}

// ---------------- launcher ----------------
extern "C" void kernel_launch(void* const* d_in, const int* in_sizes, int n_in,
                              void* d_out, int out_size, void* d_ws, size_t ws_size,
                              hipStream_t stream) {
    const int*   su    = (const int*)d_in[0];
    const float* emb   = (const float*)d_in[1];
    const float* convK = (const float*)d_in[2];
    const float* convb = (const float*)d_in[3];
    // d_in[4] Wi, d_in[5] Wj, d_in[6] Vv: dead in the reference (attn == identity)
    const float* fc1W  = (const float*)d_in[7];
    const float* fc1b  = (const float*)d_in[8];
    const float* fc2W  = (const float*)d_in[9];
    const float* fc2b  = (const float*)d_in[10];
    float* out = (float*)d_out;

    char* ws = (char*)d_ws;
    float* eu_sum = (float*)ws;                                    // 512 B
    __hip_bfloat16* Abf = (__hip_bfloat16*)(ws + 512);             // 2048*256*2 = 1 MB
    __hip_bfloat16* Bbf = (__hip_bfloat16*)(ws + 512 + (size_t)S_LEN * 256 * 2);

    hipMemsetAsync(eu_sum, 0, 128 * sizeof(float), stream);
    eu_kernel<<<48, 128, 0, stream>>>(su, emb, eu_sum);
    convB_kernel<<<(NPAD * 256 / 8) / 256, 256, 0, stream>>>(fc2W, Bbf);
    persample_kernel<<<S_LEN, 128, 0, stream>>>(su, emb, convK, convb,
                                                fc1W, fc1b, eu_sum, Abf);
    gemm_kernel<<<dim3(16, 391), 256, 0, stream>>>((const bf16_t*)Abf, (const bf16_t*)Bbf,
                                                   fc2b, out);
}

// Round 6
// 632.331 us; speedup vs baseline: 1.0320x; 1.0320x over previous
//
#include <hip/hip_runtime.h>
#include <hip/hip_bf16.h>

// ---------------- types ----------------
typedef __bf16 bf16_t;
typedef bf16_t bf16x8 __attribute__((ext_vector_type(8)));
typedef float f32x4 __attribute__((ext_vector_type(4)));

#define S_LEN 2048
#define L_LEN 3
#define D_DIM 128
#define NK 16
#define VOCAB 50000
#define NPAD 50048   // 391 * 128

__device__ __forceinline__ void gload16(const void* g, void* l) {
    __builtin_amdgcn_global_load_lds(
        (const __attribute__((address_space(1))) void*)g,
        (__attribute__((address_space(3))) void*)l, 16, 0, 0);
}

// ---------------- Eu: mean of 6144 gathered embedding rows ----------------
__global__ __launch_bounds__(128) void eu_kernel(const int* __restrict__ su,
                                                 const float* __restrict__ emb,
                                                 float* __restrict__ eu_sum) {
    const int t = threadIdx.x;
    const int b = blockIdx.x;           // 48 blocks, 128 rows each
    float acc = 0.f;
    for (int i = 0; i < 128; ++i) {
        int tok = su[b * 128 + i];
        acc += emb[(size_t)tok * D_DIM + t];
    }
    atomicAdd(&eu_sum[t], acc);
}

// ---------------- fc2W fp32 -> bf16, padded to NPAD rows ----------------
__global__ __launch_bounds__(256) void convB_kernel(const float* __restrict__ W,
                                                    __hip_bfloat16* __restrict__ Bb) {
    size_t gid = (size_t)blockIdx.x * 256 + threadIdx.x;
    size_t base = gid * 8;                      // element index in [NPAD*256]
    int row = (int)(base >> 8);
    float v[8];
    if (row < VOCAB) {
        float4 a = *(const float4*)&W[base];
        float4 b = *(const float4*)&W[base + 4];
        v[0]=a.x; v[1]=a.y; v[2]=a.z; v[3]=a.w; v[4]=b.x; v[5]=b.y; v[6]=b.z; v[7]=b.w;
    } else {
        #pragma unroll
        for (int i = 0; i < 8; ++i) v[i] = 0.f;
    }
    union { __hip_bfloat16 h[8]; uint4 u; } o;
    #pragma unroll
    for (int i = 0; i < 8; ++i) o.h[i] = __float2bfloat16(v[i]);
    *(uint4*)&Bb[base] = o.u;
}

// ---------------- fc1W [128][400] -> fc1Wt [400][128] (coalesced consumer) ----------------
__global__ __launch_bounds__(256) void transpW_kernel(const float* __restrict__ W,
                                                      float* __restrict__ Wt) {
    int idx = blockIdx.x * 256 + threadIdx.x;   // 200 blocks -> 51200
    int x = idx >> 7, e = idx & 127;
    Wt[idx] = W[e * 400 + x];
}

// ---------------- fused per-sample pipeline ----------------
// NOTE: the reference's Bahdanau attention is an IDENTITY on Ec:
//   attn[b,s,i,d] = sum_j alpha[i,j] * Ec[b,s,i,d] = Ec[b,s,i,d]
// (Ec[:, :, :, None, :] aligns l with i, and softmax_j sums to 1), so
// Wi/Wj/Vv are dead parameters. fc1_in = [conv(16), Ec flat(384)].
__global__ __launch_bounds__(128) void persample_kernel(
    const int* __restrict__ su, const float* __restrict__ emb,
    const float* __restrict__ convK, const float* __restrict__ convb,
    const float* __restrict__ fc1Wt, const float* __restrict__ fc1b,
    const float* __restrict__ eu_sum, __hip_bfloat16* __restrict__ Abf) {
    __shared__ __align__(16) float fc1_in[NK + L_LEN * D_DIM];  // 400
    __shared__ float hbuf[D_DIM];
    __shared__ float redk[NK][2];
    const int s = blockIdx.x;
    const int t = threadIdx.x;
    const int lane = t & 63, w = t >> 6;

    float ecr[L_LEN];
    #pragma unroll
    for (int li = 0; li < L_LEN; ++li) {
        int tok = su[s * L_LEN + li];
        ecr[li] = emb[(size_t)tok * D_DIM + t];
        fc1_in[NK + li * D_DIM + t] = ecr[li];   // attn == Ec (identity)
    }
    const float Eut = eu_sum[t] * (1.0f / 6144.0f);

    // vertical conv partials: each wave reduces its 64 d-lanes for all k
    for (int k = 0; k < NK; ++k) {
        float p = 0.f;
        #pragma unroll
        for (int li = 0; li < L_LEN; ++li)
            p += ecr[li] * convK[k * (L_LEN * D_DIM) + li * D_DIM + t];
        #pragma unroll
        for (int off = 32; off > 0; off >>= 1) p += __shfl_down(p, off, 64);
        if (lane == 0) redk[k][w] = p;
    }
    __syncthreads();
    if (t < NK) fc1_in[t] = fmaxf(redk[t][0] + redk[t][1] + convb[t], 0.f);
    __syncthreads();

    // fc1 via transposed weights: h[t] = relu(sum_x fc1_in[x]*fc1Wt[x][t] + b[t])
    {
        float acc = fc1b[t];
        #pragma unroll 4
        for (int x = 0; x < 400; ++x)
            acc += fc1_in[x] * fc1Wt[x * 128 + t];   // coalesced across lanes
        hbuf[t] = fmaxf(acc, 0.f);
    }
    __syncthreads();

    // second attention: u[i] = sum_j softmax_j(Eu[i]*h[j]) * h[j];  thread t = i
    {
        float m = -1e30f;
        for (int j = 0; j < D_DIM; ++j) m = fmaxf(m, Eut * hbuf[j]);
        float se = 0.f, sw = 0.f;
        for (int j = 0; j < D_DIM; ++j) {
            float e = __expf(Eut * hbuf[j] - m);
            se += e; sw += e * hbuf[j];
        }
        float u = sw / se;
        Abf[(size_t)s * 256 + t]       = __float2bfloat16(Eut);
        Abf[(size_t)s * 256 + 128 + t] = __float2bfloat16(u);
    }
}

// ---------------- bf16 MFMA GEMM: C[2048][50000] = A[2048][256] * B[NPAD][256]^T ----------------
// 128x128 tile, BK=64, double-buffered LDS (2-phase pipeline, raw barriers +
// counted vmcnt), XCD-swizzled block ids, LDS-staged coalesced epilogue.
__global__ __launch_bounds__(256) void gemm_kernel(const bf16_t* __restrict__ A,
                                                   const bf16_t* __restrict__ B,
                                                   const float* __restrict__ bias,
                                                   float* __restrict__ out) {
    __shared__ __align__(16) unsigned char lds[2][32768];  // per buf: A 16K | B 16K
    const int tid = threadIdx.x;
    const int l = tid & 63;
    const int w = tid >> 6;
    const int wm = w >> 1, wn = w & 1;

    // bijective XCD swizzle: 6256 blocks = 8 * 782
    const int bid = blockIdx.x;
    const int swz = (bid & 7) * 782 + (bid >> 3);
    const int m0 = (swz & 15) * 128;
    const int n0 = (swz >> 4) * 128;

    f32x4 acc[4][4] = {};

    const char* Ab = (const char*)A + (size_t)m0 * 512;  // 256 bf16 = 512B row stride
    const char* Bb = (const char*)B + (size_t)n0 * 512;
    const int srow = tid >> 3;                           // 0..31
    const int scolb = ((tid & 7) ^ (srow & 7)) << 4;     // pre-swizzled source chunk

#define STAGE(p, kk)                                                              \
    {                                                                             \
        _Pragma("unroll")                                                         \
        for (int i = 0; i < 4; ++i)                                               \
            gload16(Ab + (size_t)(srow + i * 32) * 512 + (kk) * 128 + scolb,      \
                    &lds[p][i * 4096 + w * 1024]);                                \
        _Pragma("unroll")                                                         \
        for (int i = 0; i < 4; ++i)                                               \
            gload16(Bb + (size_t)(srow + i * 32) * 512 + (kk) * 128 + scolb,      \
                    &lds[p][16384 + i * 4096 + w * 1024]);                        \
    }

    STAGE(0, 0);
    asm volatile("s_waitcnt vmcnt(0)" ::: "memory");
    __builtin_amdgcn_sched_barrier(0);
    __builtin_amdgcn_s_barrier();

    #pragma unroll
    for (int kk = 0; kk < 4; ++kk) {
        const int cur = kk & 1;
        if (kk < 3) STAGE(cur ^ 1, kk + 1);
        #pragma unroll
        for (int kh = 0; kh < 2; ++kh) {
            const int koff = kh * 64 + (l >> 4) * 16;
            bf16x8 af[4], bfr[4];
            #pragma unroll
            for (int mi = 0; mi < 4; ++mi) {
                int row = wm * 64 + mi * 16 + (l & 15);
                af[mi] = *(const bf16x8*)&lds[cur][row * 128 + (koff ^ ((row & 7) << 4))];
            }
            #pragma unroll
            for (int ni = 0; ni < 4; ++ni) {
                int row = wn * 64 + ni * 16 + (l & 15);
                bfr[ni] = *(const bf16x8*)&lds[cur][16384 + row * 128 + (koff ^ ((row & 7) << 4))];
            }
            #pragma unroll
            for (int mi = 0; mi < 4; ++mi)
                #pragma unroll
                for (int ni = 0; ni < 4; ++ni)
                    acc[mi][ni] = __builtin_amdgcn_mfma_f32_16x16x32_bf16(
                        af[mi], bfr[ni], acc[mi][ni], 0, 0, 0);
        }
        asm volatile("s_waitcnt vmcnt(0)" ::: "memory");  // next-stage loads landed
        __builtin_amdgcn_sched_barrier(0);
        __builtin_amdgcn_s_barrier();
    }
#undef STAGE

    // ---- epilogue: LDS-staged transpose -> coalesced float4 stores ----
    float* lout = (float*)&lds[0][0];   // 64 rows x 132 floats (padded) = 33 KB
    #pragma unroll
    for (int h = 0; h < 2; ++h) {
        if (wm == h) {
            #pragma unroll
            for (int ni = 0; ni < 4; ++ni)
                #pragma unroll
                for (int mi = 0; mi < 4; ++mi) {
                    int r0 = mi * 16 + (l >> 4) * 4;
                    int c  = wn * 64 + ni * 16 + (l & 15);
                    f32x4 v = acc[mi][ni];
                    #pragma unroll
                    for (int r = 0; r < 4; ++r) lout[(r0 + r) * 132 + c] = v[r];
                }
        }
        __syncthreads();
        #pragma unroll
        for (int i = 0; i < 8; ++i) {
            int idx = tid + 256 * i;          // 0..2047
            int row = idx >> 5;               // 0..63
            int c4  = (idx & 31) * 4;
            int col = n0 + c4;
            if (col < VOCAB) {
                float4 bv = *(const float4*)&bias[col];
                float* lp = &lout[row * 132 + c4];
                float4 v  = *(float4*)lp;
                v.x += bv.x; v.y += bv.y; v.z += bv.z; v.w += bv.w;
                *(float4*)&out[(size_t)(m0 + h * 64 + row) * VOCAB + col] = v;
            }
        }
        __syncthreads();
    }
}

// ---------------- launcher ----------------
extern "C" void kernel_launch(void* const* d_in, const int* in_sizes, int n_in,
                              void* d_out, int out_size, void* d_ws, size_t ws_size,
                              hipStream_t stream) {
    const int*   su    = (const int*)d_in[0];
    const float* emb   = (const float*)d_in[1];
    const float* convK = (const float*)d_in[2];
    const float* convb = (const float*)d_in[3];
    // d_in[4] Wi, d_in[5] Wj, d_in[6] Vv: dead in the reference (attn == identity)
    const float* fc1W  = (const float*)d_in[7];
    const float* fc1b  = (const float*)d_in[8];
    const float* fc2W  = (const float*)d_in[9];
    const float* fc2b  = (const float*)d_in[10];
    float* out = (float*)d_out;

    char* ws = (char*)d_ws;
    float* eu_sum = (float*)ws;                                     // 512 B
    __hip_bfloat16* Abf = (__hip_bfloat16*)(ws + 512);              // 1 MB
    __hip_bfloat16* Bbf = (__hip_bfloat16*)(ws + 512 + (size_t)S_LEN * 256 * 2);
    float* fc1Wt = (float*)(ws + 512 + (size_t)S_LEN * 256 * 2 + (size_t)NPAD * 256 * 2);

    hipMemsetAsync(eu_sum, 0, 128 * sizeof(float), stream);
    eu_kernel<<<48, 128, 0, stream>>>(su, emb, eu_sum);
    convB_kernel<<<(NPAD * 256 / 8) / 256, 256, 0, stream>>>(fc2W, Bbf);
    transpW_kernel<<<200, 256, 0, stream>>>(fc1W, fc1Wt);
    persample_kernel<<<S_LEN, 128, 0, stream>>>(su, emb, convK, convb,
                                                fc1Wt, fc1b, eu_sum, Abf);
    gemm_kernel<<<6256, 256, 0, stream>>>((const bf16_t*)Abf, (const bf16_t*)Bbf,
                                          fc2b, out);
}